// Round 11
// baseline (268.931 us; speedup 1.0000x reference)
//
#include <hip/hip_runtime.h>

#define NN 100000
#define NE 1600000
#define STRIDE 64        // padded CSR row capacity; P(deg>=64) ~ 1e-14 for Poisson(16)
#define NROWG2 (NN / 8)  // 12500 exact (2 rows per wave, 8 rows per block)
#define NBUCK 196        // dst >> 9 -> 0..195 (512 rows per bucket)
#define BCAP 8960        // mean 8192 + ~8.5 sigma; drop-guarded
#define CHUNK 2048
#define NCHUNK ((NE + CHUNK - 1) / CHUNK)   // 782

typedef unsigned int uint32;
typedef unsigned short ushort16;

__device__ __forceinline__ ushort16 f2bf(float f) {
    uint32 u = __float_as_uint(f);
    u = (u + 0x7FFF + ((u >> 16) & 1)) >> 16;   // RNE
    return (ushort16)u;
}
// unpack a uint holding 2 bf16 (lo = feature 2j, hi = feature 2j+1)
__device__ __forceinline__ float bflo(uint32 u) { return __uint_as_float(u << 16); }
__device__ __forceinline__ float bfhi(uint32 u) { return __uint_as_float(u & 0xffff0000u); }

// ---------- Phase A: bucket edges; staging entry packed to 26 bits ----------
__global__ void k_bucketA(const int* __restrict__ src, const int* __restrict__ dst,
                          int* gcur, uint32* __restrict__ stage) {
    __shared__ int lcnt[NBUCK];
    __shared__ int lbase[NBUCK];
    int t = threadIdx.x;
    int e0 = blockIdx.x * CHUNK;
    if (t < NBUCK) lcnt[t] = 0;
    __syncthreads();
    uint32 v[8]; int b[8], lp[8];
    int m = 0;
#pragma unroll
    for (int jj = 0; jj < 8; jj++) {
        int e = e0 + jj * 256 + t;
        if (e < NE) {
            int s = src[e], d = dst[e];
            b[jj] = d >> 9;
            v[jj] = ((uint32)(d & 511) << 17) | (uint32)s;   // src < 2^17
            lp[jj] = atomicAdd(&lcnt[b[jj]], 1);
            m = jj + 1;
        }
    }
    __syncthreads();
    if (t < NBUCK) lbase[t] = atomicAdd(&gcur[t], lcnt[t]);
    __syncthreads();
    for (int jj = 0; jj < m; jj++) {
        int pos = lbase[b[jj]] + lp[jj];
        if (pos < BCAP) stage[(size_t)b[jj] * BCAP + pos] = v[jj];
    }
}

// ---------- Phase B: one WG per bucket; CSR build + pad-to-16 + counts(dis)
// + FUSED prescale of this bucket's rows (coalesced x reads) ----------
__global__ __launch_bounds__(512)
void k_buildB(const int* __restrict__ gcur, const uint32* __restrict__ stage,
              const float* __restrict__ X,
              int* __restrict__ counts, float* __restrict__ dis,
              int* __restrict__ csr, uint32* __restrict__ Xb, uint32* __restrict__ Hbz) {
    __shared__ int lcnt[512];
    __shared__ float ldis[512];
    int b = blockIdx.x, t = threadIdx.x;
    lcnt[t] = 0;
    __syncthreads();
    int n = gcur[b]; if (n > BCAP) n = BCAP;
    const uint32* sp = stage + (size_t)b * BCAP;
    for (int i = t; i < n; i += 512) {
        uint32 p = sp[i];
        int ssrc = (int)(p & 0x1FFFFu);
        int dl = (int)(p >> 17);
        int lpos = atomicAdd(&lcnt[dl], 1);
        if (lpos < STRIDE) csr[(size_t)((b << 9) + dl) * STRIDE + lpos] = ssrc;
    }
    __syncthreads();
    int base = b << 9;
    int r0 = base + t;
    if (r0 < NN) {
        int c = lcnt[t]; if (c > STRIDE) c = STRIDE;
        int ce = (c + 15) & ~15;           // pad to multiple of 16 (<= STRIDE)
        counts[r0] = ce;                   // store PADDED count (layers use this)
        float dd = rsqrtf((float)c + 1.0f);
        dis[r0] = dd;
        ldis[t] = dd;
        for (int i = c; i < ce; ++i) csr[(size_t)r0 * STRIDE + i] = NN;
    }
    __syncthreads();
    // fused prescale: Xb rows of this bucket, coalesced
    for (int pi = t; pi < 512 * 32; pi += 512) {
        int rl = pi >> 5;
        int r = base + rl;
        if (r < NN) {
            float dd = ldis[rl];
            float2 vv = ((const float2*)X)[(size_t)r * 32 + (pi & 31)];
            uint32 a = (uint32)f2bf(vv.x * dd);
            uint32 bb = (uint32)f2bf(vv.y * dd);
            Xb[(size_t)r * 32 + (pi & 31)] = a | (bb << 16);
        }
    }
    if (b == NBUCK - 1 && t < 32) {        // reserved zero row NN in both buffers
        Xb[(size_t)NN * 32 + t] = 0u;
        Hbz[(size_t)NN * 32 + t] = 0u;
    }
}

// ---------- layer 1: 2-row interleaved pair-gather, tail-free, W in VGPRs ----------
__global__ __launch_bounds__(256, 3)
void k_layer1(const uint32* __restrict__ Xb32, const int* __restrict__ counts,
              const int* __restrict__ csr, const float* __restrict__ dis,
              const float* __restrict__ W1, const float* __restrict__ b1,
              ushort16* __restrict__ Hb) {
    __shared__ __align__(16) float accs[4][2][64];
    int t = threadIdx.x, lane = t & 63, wid = t >> 6;
    int half = lane >> 5, j = lane & 31;
    float Wreg[64];
#pragma unroll
    for (int k = 0; k < 64; k++) Wreg[k] = W1[k * 64 + lane];
    float bl = b1[lane];

    for (int g = blockIdx.x; g < NROWG2; g += gridDim.x) {
        int rA = g * 8 + wid;
        int rB = rA + 4;
        float drA = dis[rA], drB = dis[rB];
        uint32 uA0 = half ? 0u : Xb32[(size_t)rA * 32 + j];   // self-loop, half 0 only
        uint32 uB0 = half ? 0u : Xb32[(size_t)rB * 32 + j];
        float aAL = bflo(uA0), aAH = bfhi(uA0);
        float aBL = bflo(uB0), aBH = bfhi(uB0);
        int ceA = counts[rA], ceB = counts[rB];
        int ce = ceA > ceB ? ceA : ceB;
        const int* cpA = csr + (size_t)rA * STRIDE;
        const int* cpB = csr + (size_t)rB * STRIDE;
        for (int i = 0; i < ce; i += 16) {
            bool vA = i < ceA, vB = i < ceB;   // ce's are multiples of 16
#pragma unroll
            for (int p = 0; p < 8; p++) {
                int a0 = cpA[i + 2 * p], a1 = cpA[i + 2 * p + 1];
                int c0 = cpB[i + 2 * p], c1 = cpB[i + 2 * p + 1];
                int sA = half ? a1 : a0;  sA = vA ? sA : NN;
                int sB = half ? c1 : c0;  sB = vB ? sB : NN;
                uint32 uA = Xb32[(size_t)sA * 32 + j];
                uint32 uB = Xb32[(size_t)sB * 32 + j];
                aAL += bflo(uA); aAH += bfhi(uA);
                aBL += bflo(uB); aBH += bfhi(uB);
            }
        }
        aAL += __shfl_xor(aAL, 32); aAH += __shfl_xor(aAH, 32);
        aBL += __shfl_xor(aBL, 32); aBH += __shfl_xor(aBH, 32);
        if (lane < 32) {
            accs[wid][0][2 * j] = aAL; accs[wid][0][2 * j + 1] = aAH;
            accs[wid][1][2 * j] = aBL; accs[wid][1][2 * j + 1] = aBH;
        }
        float o0 = 0.f, o1 = 0.f, o2 = 0.f, o3 = 0.f;
        float q0 = 0.f, q1 = 0.f, q2 = 0.f, q3 = 0.f;
#pragma unroll
        for (int k4 = 0; k4 < 16; k4++) {
            float4 qa = *reinterpret_cast<const float4*>(&accs[wid][0][k4 * 4]);
            float4 qb = *reinterpret_cast<const float4*>(&accs[wid][1][k4 * 4]);
            o0 = fmaf(qa.x, Wreg[k4 * 4 + 0], o0);
            o1 = fmaf(qa.y, Wreg[k4 * 4 + 1], o1);
            o2 = fmaf(qa.z, Wreg[k4 * 4 + 2], o2);
            o3 = fmaf(qa.w, Wreg[k4 * 4 + 3], o3);
            q0 = fmaf(qb.x, Wreg[k4 * 4 + 0], q0);
            q1 = fmaf(qb.y, Wreg[k4 * 4 + 1], q1);
            q2 = fmaf(qb.z, Wreg[k4 * 4 + 2], q2);
            q3 = fmaf(qb.w, Wreg[k4 * 4 + 3], q3);
        }
        float oA = (o0 + o1) + (o2 + o3);
        float oB = (q0 + q1) + (q2 + q3);
        float hA = fmaxf(fmaf(oA, drA, bl), 0.f);
        float hB = fmaxf(fmaf(oB, drB, bl), 0.f);
        Hb[(size_t)rA * 64 + lane] = f2bf(hA * drA);
        Hb[(size_t)rB * 64 + lane] = f2bf(hB * drB);
    }
}

// ---------- layer 2 + output head (same 2-row structure) ----------
__global__ __launch_bounds__(256, 3)
void k_layer2(const uint32* __restrict__ Hb32, const int* __restrict__ counts,
              const int* __restrict__ csr, const float* __restrict__ dis,
              const float* __restrict__ W2, const float* __restrict__ b2,
              const float* __restrict__ Wout, const float* __restrict__ bout,
              float* __restrict__ y) {
    __shared__ __align__(16) float accs[4][2][64];
    int t = threadIdx.x, lane = t & 63, wid = t >> 6;
    int half = lane >> 5, j = lane & 31;
    float Wreg[64];
#pragma unroll
    for (int k = 0; k < 64; k++) Wreg[k] = W2[k * 64 + lane];
    float bl = b2[lane];
    float wl = Wout[lane];
    float bo = bout[0];

    for (int g = blockIdx.x; g < NROWG2; g += gridDim.x) {
        int rA = g * 8 + wid;
        int rB = rA + 4;
        float drA = dis[rA], drB = dis[rB];
        uint32 uA0 = half ? 0u : Hb32[(size_t)rA * 32 + j];
        uint32 uB0 = half ? 0u : Hb32[(size_t)rB * 32 + j];
        float aAL = bflo(uA0), aAH = bfhi(uA0);
        float aBL = bflo(uB0), aBH = bfhi(uB0);
        int ceA = counts[rA], ceB = counts[rB];
        int ce = ceA > ceB ? ceA : ceB;
        const int* cpA = csr + (size_t)rA * STRIDE;
        const int* cpB = csr + (size_t)rB * STRIDE;
        for (int i = 0; i < ce; i += 16) {
            bool vA = i < ceA, vB = i < ceB;
#pragma unroll
            for (int p = 0; p < 8; p++) {
                int a0 = cpA[i + 2 * p], a1 = cpA[i + 2 * p + 1];
                int c0 = cpB[i + 2 * p], c1 = cpB[i + 2 * p + 1];
                int sA = half ? a1 : a0;  sA = vA ? sA : NN;
                int sB = half ? c1 : c0;  sB = vB ? sB : NN;
                uint32 uA = Hb32[(size_t)sA * 32 + j];
                uint32 uB = Hb32[(size_t)sB * 32 + j];
                aAL += bflo(uA); aAH += bfhi(uA);
                aBL += bflo(uB); aBH += bfhi(uB);
            }
        }
        aAL += __shfl_xor(aAL, 32); aAH += __shfl_xor(aAH, 32);
        aBL += __shfl_xor(aBL, 32); aBH += __shfl_xor(aBH, 32);
        if (lane < 32) {
            accs[wid][0][2 * j] = aAL; accs[wid][0][2 * j + 1] = aAH;
            accs[wid][1][2 * j] = aBL; accs[wid][1][2 * j + 1] = aBH;
        }
        float o0 = 0.f, o1 = 0.f, o2 = 0.f, o3 = 0.f;
        float q0 = 0.f, q1 = 0.f, q2 = 0.f, q3 = 0.f;
#pragma unroll
        for (int k4 = 0; k4 < 16; k4++) {
            float4 qa = *reinterpret_cast<const float4*>(&accs[wid][0][k4 * 4]);
            float4 qb = *reinterpret_cast<const float4*>(&accs[wid][1][k4 * 4]);
            o0 = fmaf(qa.x, Wreg[k4 * 4 + 0], o0);
            o1 = fmaf(qa.y, Wreg[k4 * 4 + 1], o1);
            o2 = fmaf(qa.z, Wreg[k4 * 4 + 2], o2);
            o3 = fmaf(qa.w, Wreg[k4 * 4 + 3], o3);
            q0 = fmaf(qb.x, Wreg[k4 * 4 + 0], q0);
            q1 = fmaf(qb.y, Wreg[k4 * 4 + 1], q1);
            q2 = fmaf(qb.z, Wreg[k4 * 4 + 2], q2);
            q3 = fmaf(qb.w, Wreg[k4 * 4 + 3], q3);
        }
        float vA = fmaxf(fmaf((o0 + o1) + (o2 + o3), drA, bl), 0.f) * wl;
        float vB = fmaxf(fmaf((q0 + q1) + (q2 + q3), drB, bl), 0.f) * wl;
#pragma unroll
        for (int off = 32; off; off >>= 1) { vA += __shfl_down(vA, off); vB += __shfl_down(vB, off); }
        if (lane == 0) { y[rA] = vA + bo; y[rB] = vB + bo; }
    }
}

extern "C" void kernel_launch(void* const* d_in, const int* in_sizes, int n_in,
                              void* d_out, int out_size, void* d_ws, size_t ws_size,
                              hipStream_t stream) {
    const float* x    = (const float*)d_in[0];
    const int*   ei   = (const int*)d_in[1];
    const int*   src  = ei;            // edge_index[0]
    const int*   dst  = ei + NE;       // edge_index[1]
    const float* W1   = (const float*)d_in[2];
    const float* b1   = (const float*)d_in[3];
    const float* W2   = (const float*)d_in[4];
    const float* b2   = (const float*)d_in[5];
    const float* Wout = (const float*)d_in[6];
    const float* bout = (const float*)d_in[7];
    float* y = (float*)d_out;

    char* ws = (char*)d_ws;
    int*      gcur   = (int*)ws;      ws += 1024;                      // NBUCK ints
    int*      counts = (int*)ws;      ws += 400128;                    // NN ints (PADDED counts)
    float*    dis    = (float*)ws;    ws += 400128;                    // NN floats
    int*      csr    = (int*)ws;      ws += (size_t)NN * STRIDE * 4;   // 25.6 MB
    uint32*   Xb     = (uint32*)ws;   ws += (size_t)(NN + 1) * 64 * 2; // 12.8 MB (+zero row)
    uint32*   Hb     = (uint32*)ws;                                     // 12.8 MB (+zero row)
    // packed staging (7.0 MB) aliases Hb (dead until layer1 writes it; buildB
    // writes Xb + zero rows only, which don't overlap the staging region)
    uint32*   stage  = Hb;

    hipMemsetAsync(gcur, 0, NBUCK * sizeof(int), stream);
    k_bucketA<<<NCHUNK, 256, 0, stream>>>(src, dst, gcur, stage);
    k_buildB<<<NBUCK, 512, 0, stream>>>(gcur, stage, x, counts, dis, csr, Xb, Hb);

    k_layer1<<<2048, 256, 0, stream>>>(Xb, counts, csr, dis, W1, b1, (ushort16*)Hb);
    k_layer2<<<2048, 256, 0, stream>>>(Hb, counts, csr, dis, W2, b2, Wout, bout, y);
}

// Round 13
// 249.194 us; speedup vs baseline: 1.0792x; 1.0792x over previous
//
#include <hip/hip_runtime.h>

#define NN 100000
#define NE 1600000
#define STRIDE 64        // padded CSR row capacity; P(deg>=64) ~ 1e-14 for Poisson(16)
#define NROWG (NN / 4)   // 25000 exact
#define NBUCK 196        // dst >> 9 -> 0..195 (512 rows per bucket)
#define BCAP 8960        // mean 8192 + ~8.5 sigma; drop-guarded
#define CHUNK 2048
#define NCHUNK ((NE + CHUNK - 1) / CHUNK)   // 782

typedef unsigned int uint32;
typedef unsigned short ushort16;

__device__ __forceinline__ ushort16 f2bf(float f) {
    uint32 u = __float_as_uint(f);
    u = (u + 0x7FFF + ((u >> 16) & 1)) >> 16;   // RNE
    return (ushort16)u;
}
// unpack a uint holding 2 bf16 (lo = feature 2j, hi = feature 2j+1)
__device__ __forceinline__ float bflo(uint32 u) { return __uint_as_float(u << 16); }
__device__ __forceinline__ float bfhi(uint32 u) { return __uint_as_float(u & 0xffff0000u); }

// ---------- Phase A: bucket edges by dst-range into per-bucket staging ----------
__global__ void k_bucketA(const int* __restrict__ src, const int* __restrict__ dst,
                          int* gcur, uint2* __restrict__ stage) {
    __shared__ int lcnt[NBUCK];
    __shared__ int lbase[NBUCK];
    int t = threadIdx.x;
    int e0 = blockIdx.x * CHUNK;
    if (t < NBUCK) lcnt[t] = 0;
    __syncthreads();
    int s[8], d[8], b[8], lp[8];
    int m = 0;
#pragma unroll
    for (int j = 0; j < 8; j++) {
        int e = e0 + j * 256 + t;
        if (e < NE) {
            s[j] = src[e];
            d[j] = dst[e];
            b[j] = d[j] >> 9;
            lp[j] = atomicAdd(&lcnt[b[j]], 1);
            m = j + 1;
        }
    }
    __syncthreads();
    if (t < NBUCK) lbase[t] = atomicAdd(&gcur[t], lcnt[t]);
    __syncthreads();
    for (int j = 0; j < m; j++) {
        int pos = lbase[b[j]] + lp[j];
        if (pos < BCAP) stage[(size_t)b[j] * BCAP + pos] = make_uint2((uint32)s[j], (uint32)d[j]);
    }
}

// ---------- Phase B: one WG per bucket; LDS counters; XCD-local CSR writes;
// pads every CSR row to a multiple of 16 with the zero-row index NN ----------
__global__ __launch_bounds__(512)
void k_buildB(const int* __restrict__ gcur, const uint2* __restrict__ stage,
              int* __restrict__ counts, float* __restrict__ dis, int* __restrict__ csr) {
    __shared__ int lcnt[512];
    int b = blockIdx.x, t = threadIdx.x;
    if (t < 512) lcnt[t] = 0;
    __syncthreads();
    int n = gcur[b]; if (n > BCAP) n = BCAP;
    const uint2* sp = stage + (size_t)b * BCAP;
    for (int i = t; i < n; i += 512) {
        uint2 p = sp[i];
        int dd = (int)p.y;
        int lpos = atomicAdd(&lcnt[dd & 511], 1);
        if (lpos < STRIDE) csr[(size_t)dd * STRIDE + lpos] = (int)p.x;
    }
    __syncthreads();
    int base = b << 9;
    int r = base + t;
    if (t < 512 && r < NN) {
        int c = lcnt[t]; if (c > STRIDE) c = STRIDE;
        counts[r] = c;
        dis[r] = rsqrtf((float)c + 1.0f);
        int ce = (c + 15) & ~15;           // pad to multiple of 16 (<= STRIDE)
        for (int i = c; i < ce; ++i) csr[(size_t)r * STRIDE + i] = NN;
    }
}

// Xb[r][j] = bf16(x[r][j] * dis[r]); also zeroes the reserved zero-row NN in Xb AND Hb
__global__ void k_prescale(const float* __restrict__ X, const float* __restrict__ dis,
                           uint32* __restrict__ Xb, uint32* __restrict__ Hbz) {
    int i = blockIdx.x * blockDim.x + threadIdx.x;   // pair index
    if (i >= NN * 32) {
        if (i < NN * 32 + 32) { Xb[i] = 0u; Hbz[i] = 0u; }
        return;
    }
    float dd = dis[i >> 5];
    float2 v = ((const float2*)X)[i];
    uint32 a = (uint32)f2bf(v.x * dd);
    uint32 b = (uint32)f2bf(v.y * dd);
    Xb[i] = a | (b << 16);
}

// ---------- layer 1: quad-gather (4 src rows per b64 instruction), tail-free.
// lane = sg*16 + fq: src-group sg in [0,4), feature-quad fq in [0,16).
// Each inst: lanes of group sg load uint2 = feats 4fq..4fq+3 of src cp[i+4p+sg].
// Reduce across groups via shfl_xor(16,32); lanes 0-15 publish float4 to LDS;
// W column in VGPRs, LDS-broadcast matmul with 4 partial accumulators.
__global__ __launch_bounds__(256, 4)
void k_layer1(const uint2* __restrict__ Xb2, const int* __restrict__ counts,
              const int* __restrict__ csr, const float* __restrict__ dis,
              const float* __restrict__ W1, const float* __restrict__ b1,
              ushort16* __restrict__ Hb) {
    __shared__ __align__(16) float accs[4][64];
    int t = threadIdx.x, lane = t & 63, wid = t >> 6;
    int fq = lane & 15, sg = lane >> 4;
    float Wreg[64];
#pragma unroll
    for (int k = 0; k < 64; k++) Wreg[k] = W1[k * 64 + lane];
    float bl = b1[lane];

    for (int g = blockIdx.x; g < NROWG; g += gridDim.x) {
        int row = g * 4 + wid;
        float dr = dis[row];
        // self-loop: src-group 0 only (others contribute 0; summed in reduce)
        uint2 u0 = (sg == 0) ? Xb2[(size_t)row * 16 + fq] : make_uint2(0u, 0u);
        float a0 = bflo(u0.x), a1 = bfhi(u0.x), a2 = bflo(u0.y), a3 = bfhi(u0.y);
        int ce = (counts[row] + 15) & ~15;   // padded bound, entries all valid
        const int* cp = csr + (size_t)row * STRIDE;
        for (int i = 0; i < ce; i += 16) {
#pragma unroll
            for (int p = 0; p < 4; p++) {
                int s = cp[i + 4 * p + sg];
                uint2 u = Xb2[(size_t)s * 16 + fq];
                a0 += bflo(u.x); a1 += bfhi(u.x);
                a2 += bflo(u.y); a3 += bfhi(u.y);
            }
        }
        a0 += __shfl_xor(a0, 16); a1 += __shfl_xor(a1, 16);
        a2 += __shfl_xor(a2, 16); a3 += __shfl_xor(a3, 16);
        a0 += __shfl_xor(a0, 32); a1 += __shfl_xor(a1, 32);
        a2 += __shfl_xor(a2, 32); a3 += __shfl_xor(a3, 32);
        if (lane < 16) {
            *reinterpret_cast<float4*>(&accs[wid][fq * 4]) = make_float4(a0, a1, a2, a3);
        }
        float o0 = 0.f, o1 = 0.f, o2 = 0.f, o3 = 0.f;
#pragma unroll
        for (int k4 = 0; k4 < 16; k4++) {
            float4 q = *reinterpret_cast<const float4*>(&accs[wid][k4 * 4]);  // uniform addr: broadcast
            o0 = fmaf(q.x, Wreg[k4 * 4 + 0], o0);
            o1 = fmaf(q.y, Wreg[k4 * 4 + 1], o1);
            o2 = fmaf(q.z, Wreg[k4 * 4 + 2], o2);
            o3 = fmaf(q.w, Wreg[k4 * 4 + 3], o3);
        }
        float o = (o0 + o1) + (o2 + o3);
        float h = fmaxf(fmaf(o, dr, bl), 0.f);
        Hb[(size_t)row * 64 + lane] = f2bf(h * dr);
    }
}

// ---------- layer 2 + output head (same quad-gather structure) ----------
__global__ __launch_bounds__(256, 4)
void k_layer2(const uint2* __restrict__ Hb2, const int* __restrict__ counts,
              const int* __restrict__ csr, const float* __restrict__ dis,
              const float* __restrict__ W2, const float* __restrict__ b2,
              const float* __restrict__ Wout, const float* __restrict__ bout,
              float* __restrict__ y) {
    __shared__ __align__(16) float accs[4][64];
    int t = threadIdx.x, lane = t & 63, wid = t >> 6;
    int fq = lane & 15, sg = lane >> 4;
    float Wreg[64];
#pragma unroll
    for (int k = 0; k < 64; k++) Wreg[k] = W2[k * 64 + lane];
    float bl = b2[lane];
    float wl = Wout[lane];
    float bo = bout[0];

    for (int g = blockIdx.x; g < NROWG; g += gridDim.x) {
        int row = g * 4 + wid;
        float dr = dis[row];
        uint2 u0 = (sg == 0) ? Hb2[(size_t)row * 16 + fq] : make_uint2(0u, 0u);
        float a0 = bflo(u0.x), a1 = bfhi(u0.x), a2 = bflo(u0.y), a3 = bfhi(u0.y);
        int ce = (counts[row] + 15) & ~15;
        const int* cp = csr + (size_t)row * STRIDE;
        for (int i = 0; i < ce; i += 16) {
#pragma unroll
            for (int p = 0; p < 4; p++) {
                int s = cp[i + 4 * p + sg];
                uint2 u = Hb2[(size_t)s * 16 + fq];
                a0 += bflo(u.x); a1 += bfhi(u.x);
                a2 += bflo(u.y); a3 += bfhi(u.y);
            }
        }
        a0 += __shfl_xor(a0, 16); a1 += __shfl_xor(a1, 16);
        a2 += __shfl_xor(a2, 16); a3 += __shfl_xor(a3, 16);
        a0 += __shfl_xor(a0, 32); a1 += __shfl_xor(a1, 32);
        a2 += __shfl_xor(a2, 32); a3 += __shfl_xor(a3, 32);
        if (lane < 16) {
            *reinterpret_cast<float4*>(&accs[wid][fq * 4]) = make_float4(a0, a1, a2, a3);
        }
        float o0 = 0.f, o1 = 0.f, o2 = 0.f, o3 = 0.f;
#pragma unroll
        for (int k4 = 0; k4 < 16; k4++) {
            float4 q = *reinterpret_cast<const float4*>(&accs[wid][k4 * 4]);
            o0 = fmaf(q.x, Wreg[k4 * 4 + 0], o0);
            o1 = fmaf(q.y, Wreg[k4 * 4 + 1], o1);
            o2 = fmaf(q.z, Wreg[k4 * 4 + 2], o2);
            o3 = fmaf(q.w, Wreg[k4 * 4 + 3], o3);
        }
        float v = fmaxf(fmaf((o0 + o1) + (o2 + o3), dr, bl), 0.f) * wl;
#pragma unroll
        for (int off = 32; off; off >>= 1) v += __shfl_down(v, off);
        if (lane == 0) y[row] = v + bo;
    }
}

extern "C" void kernel_launch(void* const* d_in, const int* in_sizes, int n_in,
                              void* d_out, int out_size, void* d_ws, size_t ws_size,
                              hipStream_t stream) {
    const float* x    = (const float*)d_in[0];
    const int*   ei   = (const int*)d_in[1];
    const int*   src  = ei;            // edge_index[0]
    const int*   dst  = ei + NE;       // edge_index[1]
    const float* W1   = (const float*)d_in[2];
    const float* b1   = (const float*)d_in[3];
    const float* W2   = (const float*)d_in[4];
    const float* b2   = (const float*)d_in[5];
    const float* Wout = (const float*)d_in[6];
    const float* bout = (const float*)d_in[7];
    float* y = (float*)d_out;

    char* ws = (char*)d_ws;
    int*      gcur   = (int*)ws;      ws += 1024;                      // NBUCK ints
    int*      counts = (int*)ws;      ws += 400128;                    // NN ints
    float*    dis    = (float*)ws;    ws += 400128;                    // NN floats
    int*      csr    = (int*)ws;      ws += (size_t)NN * STRIDE * 4;   // 25.6 MB
    uint32*   Xb     = (uint32*)ws;   ws += (size_t)(NN + 1) * 64 * 2; // 12.8 MB (+zero row)
    uint32*   Hb     = (uint32*)ws;                                     // 12.8 MB (+zero row)
    // staging (14.05 MB) aliases Xb..Hb; dead before prescale writes Xb
    uint2*    stage  = (uint2*)Xb;

    hipMemsetAsync(gcur, 0, NBUCK * sizeof(int), stream);
    k_bucketA<<<NCHUNK, 256, 0, stream>>>(src, dst, gcur, stage);
    k_buildB<<<NBUCK, 512, 0, stream>>>(gcur, stage, counts, dis, csr);
    k_prescale<<<(NN * 32 + 32 + 255) / 256, 256, 0, stream>>>(x, dis, Xb, Hb);

    k_layer1<<<2048, 256, 0, stream>>>((const uint2*)Xb, counts, csr, dis, W1, b1, (ushort16*)Hb);
    k_layer2<<<2048, 256, 0, stream>>>((const uint2*)Hb, counts, csr, dis, W2, b2, Wout, bout, y);
}